// Round 2
// baseline (152132.178 us; speedup 1.0000x reference)
//
#include <hip/hip_runtime.h>
#include <hip/hip_bf16.h>
#include <cstdint>
#include <cstddef>

#define T_LEN 16384
#define ETS 4
#define C1T 1796

typedef _Float16 half8 __attribute__((ext_vector_type(8)));
typedef float f32x4 __attribute__((ext_vector_type(4)));

// ---------------- prep: transposes + bias sums + f16 MFMA weight fragments ----------------
// Row permutation: p = 4*u + g  ->  orig row = g*256 + u   (gates i,f,g,o contiguous per unit)
__global__ void prep_kernel(const float* __restrict__ obs_w,
                            const float* __restrict__ wih0,
                            const float* __restrict__ wih1,
                            const float* __restrict__ whh0,
                            const float* __restrict__ whh1,
                            const float* __restrict__ bih0, const float* __restrict__ bhh0,
                            const float* __restrict__ bih1, const float* __restrict__ bhh1,
                            float* __restrict__ obs_wT,    // [1600][128]
                            float* __restrict__ wih0T,     // [192][1024] permuted cols, zero-pad k>=177
                            float* __restrict__ wih1T,     // [256][1024] permuted cols
                            _Float16* __restrict__ wfrag,  // [2][64rb][8kb][64lane][8]
                            float* __restrict__ bias0, float* __restrict__ bias1) {
  int i = blockIdx.x * blockDim.x + threadIdx.x;   // 2048*256 = 524288 threads
  // MFMA A-fragments of whh (f16), permuted rows
  {
    int layer = i >> 18;
    int r = i & 262143;
    int rb = r >> 12;
    int kb = (r >> 9) & 7;
    int lane = (r >> 3) & 63;
    int j = r & 7;
    int row_p = rb * 16 + (lane & 15);
    int k = kb * 32 + (lane >> 4) * 8 + j;
    int orig = (row_p & 3) * 256 + (row_p >> 2);
    const float* src = layer ? whh1 : whh0;
    wfrag[i] = (_Float16)src[orig * 256 + k];
  }
  if (i < 1600 * 128) { int k = i >> 7, o = i & 127; obs_wT[i] = obs_w[o * 1600 + k]; }
  if (i < 192 * 1024) {
    int k = i >> 10, p = i & 1023;
    int orig = (p & 3) * 256 + (p >> 2);
    wih0T[i] = (k < 177) ? wih0[orig * 177 + k] : 0.f;
  }
  if (i < 256 * 1024) {
    int k = i >> 10, p = i & 1023;
    int orig = (p & 3) * 256 + (p >> 2);
    wih1T[i] = wih1[orig * 256 + k];
  }
  if (i < 1024) {
    int orig = (i & 3) * 256 + (i >> 2);
    bias0[i] = bih0[orig] + bhh0[orig];
    bias1[i] = bih1[orig] + bhh1[orig];
  }
}

// ---------------- encoder (unchanged from round 1, verified) ----------------
__global__ __launch_bounds__(256) void encoder_kernel(
    const float* __restrict__ fov, const float* __restrict__ own_pos,
    const float* __restrict__ opponent, const float* __restrict__ cost,
    const int* __restrict__ action,
    const float* __restrict__ w1, const float* __restrict__ b1,
    const float* __restrict__ w2, const float* __restrict__ b2,
    const float* __restrict__ obs_wT, const float* __restrict__ obs_b,
    const float* __restrict__ pos_w, const float* __restrict__ pos_b,
    const float* __restrict__ opp_w, const float* __restrict__ opp_b,
    const float* __restrict__ act_emb,
    float* __restrict__ feat) {
  __shared__ float w1s[864];
  __shared__ float b1s[32];
  __shared__ float inp[ETS * 3 * 7 * 7];
  __shared__ __align__(16) float c1[ETS * C1T];
  __shared__ __align__(16) float c2s[1600 * ETS];
  __shared__ float red[4 * 128];
  int tid = threadIdx.x;
  int t0 = blockIdx.x * ETS;

  for (int i = tid; i < 864; i += 256) w1s[i] = w1[i];
  if (tid < 32) b1s[tid] = b1[tid];
  for (int i = tid; i < ETS * 3 * 49; i += 256) inp[i] = 0.f;
  for (int i = tid; i < ETS * C1T; i += 256) c1[i] = 0.f;
  __syncthreads();
  for (int i = tid; i < ETS * 75; i += 256) {
    int t = i / 75, r = i % 75;
    int y = r / 15, x = (r / 3) % 5, ch = r % 3;
    inp[((t * 3 + ch) * 7 + (y + 1)) * 7 + (x + 1)] = fov[(size_t)(t0 + t) * 75 + r];
  }
  __syncthreads();
  for (int i = tid; i < ETS * 800; i += 256) {
    int t = i / 800, r = i % 800;
    int oc = r / 25, p = r % 25, y = p / 5, x = p % 5;
    float s = b1s[oc];
#pragma unroll
    for (int ch = 0; ch < 3; ++ch)
#pragma unroll
      for (int ky = 0; ky < 3; ++ky)
#pragma unroll
        for (int kx = 0; kx < 3; ++kx)
          s += inp[((t * 3 + ch) * 7 + y + ky) * 7 + x + kx] * w1s[oc * 27 + ch * 9 + ky * 3 + kx];
    c1[t * C1T + (oc * 7 + y + 1) * 8 + (x + 1)] = fmaxf(s, 0.f);
  }
  __syncthreads();
  {
    int oc = tid >> 2, tt = tid & 3;
    float acc[25];
    float bv = b2[oc];
#pragma unroll
    for (int p = 0; p < 25; ++p) acc[p] = bv;
    for (int ic = 0; ic < 32; ++ic) {
      float pl[56];
      const float* base = &c1[tt * C1T + ic * 56];
#pragma unroll
      for (int q = 0; q < 14; ++q) {
        float4 v = *(const float4*)(base + q * 4);
        pl[q * 4 + 0] = v.x; pl[q * 4 + 1] = v.y; pl[q * 4 + 2] = v.z; pl[q * 4 + 3] = v.w;
      }
      const float* wrow = &w2[(size_t)(oc * 32 + ic) * 9];
#pragma unroll
      for (int ky = 0; ky < 3; ++ky)
#pragma unroll
        for (int kx = 0; kx < 3; ++kx) {
          float wv = wrow[ky * 3 + kx];
#pragma unroll
          for (int p = 0; p < 25; ++p) {
            int y = p / 5, x = p % 5;
            acc[p] += pl[(y + ky) * 8 + (x + kx)] * wv;
          }
        }
    }
#pragma unroll
    for (int p = 0; p < 25; ++p)
      c2s[(oc * 25 + p) * ETS + tt] = fmaxf(acc[p], 0.f);
  }
  __syncthreads();
  {
    int o = tid & 127, kh = tid >> 7;
    float a0 = 0, a1 = 0, a2 = 0, a3 = 0;
    for (int k = kh * 800; k < kh * 800 + 800; ++k) {
      float wv = obs_wT[k * 128 + o];
      float4 cv = *(const float4*)&c2s[k * ETS];
      a0 += cv.x * wv; a1 += cv.y * wv; a2 += cv.z * wv; a3 += cv.w * wv;
    }
    if (kh == 1) { red[0 * 128 + o] = a0; red[1 * 128 + o] = a1; red[2 * 128 + o] = a2; red[3 * 128 + o] = a3; }
    __syncthreads();
    if (kh == 0) {
      float ob = obs_b[o];
      feat[(size_t)(t0 + 0) * 192 + o] = a0 + red[0 * 128 + o] + ob;
      feat[(size_t)(t0 + 1) * 192 + o] = a1 + red[1 * 128 + o] + ob;
      feat[(size_t)(t0 + 2) * 192 + o] = a2 + red[2 * 128 + o] + ob;
      feat[(size_t)(t0 + 3) * 192 + o] = a3 + red[3 * 128 + o] + ob;
    }
  }
  if (tid < 64) {
    int t = tid >> 4, f = tid & 15;
    int ti = t0 + t;
    float px = own_pos[ti * 2 + 0] / 25.f, py = own_pos[ti * 2 + 1] / 25.f;
    float pe = pos_b[f] + px * pos_w[f * 2 + 0] + py * pos_w[f * 2 + 1];
    float o0 = opponent[ti * 3 + 0] / 25.f, o1 = opponent[ti * 3 + 1] / 25.f, o2 = opponent[ti * 3 + 2] / 150.f;
    float oe = opp_b[f] + o0 * opp_w[f * 3 + 0] + o1 * opp_w[f * 3 + 1] + o2 * opp_w[f * 3 + 2];
    float ae = act_emb[action[ti] * 16 + f];
    size_t fb = (size_t)ti * 192;
    feat[fb + 128 + f] = pe;
    feat[fb + 144 + f] = oe;
    feat[fb + 160 + f] = ae;
    if (f == 0) feat[fb + 176] = cost[ti];
    if (f < 15) feat[fb + 177 + f] = 0.f;
  }
}

// ---------------- fp32 tiled GEMM (unchanged, verified) ----------------
__global__ __launch_bounds__(256) void gemm_bias_kernel(
    const float* __restrict__ A, const float* __restrict__ B,
    const float* __restrict__ bias, float* __restrict__ C,
    int M, int N, int K) {
  __shared__ __align__(16) float As[32][68];
  __shared__ __align__(16) float Bs[32][68];
  int tid = threadIdx.x;
  int mb = M >> 6;
  int bm = blockIdx.x & (mb - 1);
  int bn = blockIdx.x / mb;
  int tx = tid & 15, ty = tid >> 4;
  float acc[4][4];
#pragma unroll
  for (int i = 0; i < 4; i++)
#pragma unroll
    for (int j = 0; j < 4; j++) acc[i][j] = 0.f;
  for (int k0 = 0; k0 < K; k0 += 32) {
#pragma unroll
    for (int i = 0; i < 2; ++i) {
      int id = tid + i * 256;
      int m = id >> 3, kq = id & 7;
      float4 v = *(const float4*)&A[(size_t)(bm * 64 + m) * K + k0 + kq * 4];
      As[kq * 4 + 0][m] = v.x; As[kq * 4 + 1][m] = v.y; As[kq * 4 + 2][m] = v.z; As[kq * 4 + 3][m] = v.w;
    }
#pragma unroll
    for (int i = 0; i < 2; ++i) {
      int id = tid + i * 256;
      int k = id >> 4, nq = id & 15;
      float4 v = *(const float4*)&B[(size_t)(k0 + k) * N + bn * 64 + nq * 4];
      *(float4*)&Bs[k][nq * 4] = v;
    }
    __syncthreads();
#pragma unroll
    for (int k = 0; k < 32; ++k) {
      float4 a4 = *(const float4*)&As[k][ty * 4];
      float4 b4 = *(const float4*)&Bs[k][tx * 4];
      float am[4] = {a4.x, a4.y, a4.z, a4.w};
      float bn4[4] = {b4.x, b4.y, b4.z, b4.w};
#pragma unroll
      for (int i = 0; i < 4; i++)
#pragma unroll
        for (int j = 0; j < 4; j++) acc[i][j] += am[i] * bn4[j];
    }
    __syncthreads();
  }
#pragma unroll
  for (int i = 0; i < 4; ++i) {
    int m = bm * 64 + ty * 4 + i;
    int n0 = bn * 64 + tx * 4;
    float4 o;
    o.x = acc[i][0] + bias[n0 + 0];
    o.y = acc[i][1] + bias[n0 + 1];
    o.z = acc[i][2] + bias[n0 + 2];
    o.w = acc[i][3] + bias[n0 + 3];
    *(float4*)&C[(size_t)m * N + n0] = o;
  }
}

// ---------------- single-CU MFMA LSTM layer ----------------
// 512 threads = 8 waves, one CU. Weights register-resident as f16 A-fragments
// (64 x half8 = 256 VGPR). Per step: 64 mfma_f32_16x16x32_f16 per wave
// (8 row-blocks x 8 k-blocks), D col 0 only. Permuted rows put the 4 gates of
// unit u = rb*4+(lane>>4) in acc regs 0..3 of lanes with (lane&15)==0.
// Nonlinearity distributed to threads 0..255 via SoA LDS (conflict-free).
__device__ __forceinline__ float sigf(float x) {
  return __builtin_amdgcn_rcpf(1.f + __expf(-x));
}

__global__ __launch_bounds__(512) void lstm_mfma_kernel(
    const float* __restrict__ pre,        // [T][1024] permuted gate rows
    const _Float16* __restrict__ wfrag,   // [64][8][64][8]
    float* __restrict__ hs_out,           // [T][256] or unused
    float* __restrict__ hfin, float* __restrict__ cfin,
    int write_hs) {
  __shared__ __align__(16) _Float16 hlds[2][256];
  __shared__ float zg[4][256];
  int tid = threadIdx.x;
  int wave = tid >> 6, lane = tid & 63;
  int q = lane >> 4;
  int act = ((lane & 15) == 0);

  // load weight fragments (64 x dwordx4, coalesced)
  half8 wf[8][8];
#pragma unroll
  for (int rbi = 0; rbi < 8; ++rbi)
#pragma unroll
    for (int kb = 0; kb < 8; ++kb)
      wf[rbi][kb] = *(const half8*)&wfrag[(((size_t)(wave * 8 + rbi) * 8 + kb) * 64 + lane) * 8];

  if (tid < 512) { hlds[tid >> 8][tid & 255] = (_Float16)0.f; }
  __syncthreads();

  float c = 0.f, hl = 0.f;
  for (int t = 0; t < T_LEN; ++t) {
    // prefetch pre row (consumed after barrier)
    f32x4 pv;
    if (tid < 256) pv = *(const f32x4*)&pre[(size_t)t * 1024 + tid * 4];
    // B fragments from h (f16, double-buffered LDS)
    const _Float16* hb = &hlds[t & 1][0];
    half8 bf[8];
#pragma unroll
    for (int kb = 0; kb < 8; ++kb)
      bf[kb] = *(const half8*)(hb + kb * 32 + q * 8);
    // 8 independent accumulator chains over 8 k-blocks
    f32x4 acc[8];
#pragma unroll
    for (int rbi = 0; rbi < 8; ++rbi) acc[rbi] = (f32x4){0.f, 0.f, 0.f, 0.f};
#pragma unroll
    for (int kb = 0; kb < 8; ++kb)
#pragma unroll
      for (int rbi = 0; rbi < 8; ++rbi)
        acc[rbi] = __builtin_amdgcn_mfma_f32_16x16x32_f16(wf[rbi][kb], bf[kb], acc[rbi], 0, 0, 0);
    // scatter gates to SoA LDS: zg[g][u], u = rb*4 + q (active lanes only)
    if (act) {
#pragma unroll
      for (int rbi = 0; rbi < 8; ++rbi) {
        int u = (wave * 8 + rbi) * 4 + q;
        zg[0][u] = acc[rbi].x;
        zg[1][u] = acc[rbi].y;
        zg[2][u] = acc[rbi].z;
        zg[3][u] = acc[rbi].w;
      }
    }
    __syncthreads();
    if (tid < 256) {
      float zi = zg[0][tid] + pv.x;
      float zf = zg[1][tid] + pv.y;
      float zt = zg[2][tid] + pv.z;
      float zo = zg[3][tid] + pv.w;
      float ig = sigf(zi);
      float fg = sigf(zf);
      float gg = 2.f * sigf(2.f * zt) - 1.f;
      float og = sigf(zo);
      c = fg * c + ig * gg;
      float hn = og * (2.f * sigf(2.f * c) - 1.f);
      hl = hn;
      hlds[(t + 1) & 1][tid] = (_Float16)hn;
      if (write_hs) hs_out[(size_t)t * 256 + tid] = hn;
    }
    __syncthreads();
  }
  if (tid < 256) { hfin[tid] = hl; cfin[tid] = c; }
}

// ---------------- gather outputs ----------------
__global__ void finalize_kernel(const float* __restrict__ h0, const float* __restrict__ c0,
                                const float* __restrict__ h1, const float* __restrict__ c1,
                                float* __restrict__ out) {
  int i = blockIdx.x * blockDim.x + threadIdx.x;
  if (i < 256) out[i] = h1[i];
  else if (i < 512) out[i] = h0[i - 256];
  else if (i < 768) out[i] = h1[i - 512];
  else if (i < 1024) out[i] = c0[i - 768];
  else if (i < 1280) out[i] = c1[i - 1024];
}

extern "C" void kernel_launch(void* const* d_in, const int* in_sizes, int n_in,
                              void* d_out, int out_size, void* d_ws, size_t ws_size,
                              hipStream_t stream) {
  const float* fov      = (const float*)d_in[0];
  const float* own_pos  = (const float*)d_in[1];
  const float* opponent = (const float*)d_in[2];
  const float* cost     = (const float*)d_in[3];
  const int*   action   = (const int*)d_in[4];
  const float* conv1_w  = (const float*)d_in[5];
  const float* conv1_b  = (const float*)d_in[6];
  const float* conv2_w  = (const float*)d_in[7];
  const float* conv2_b  = (const float*)d_in[8];
  const float* obs_w    = (const float*)d_in[9];
  const float* obs_b    = (const float*)d_in[10];
  const float* pos_w    = (const float*)d_in[11];
  const float* pos_b    = (const float*)d_in[12];
  const float* opp_w    = (const float*)d_in[13];
  const float* opp_b    = (const float*)d_in[14];
  const float* act_emb  = (const float*)d_in[15];
  const float* wih0     = (const float*)d_in[16];
  const float* whh0     = (const float*)d_in[17];
  const float* bih0     = (const float*)d_in[18];
  const float* bhh0     = (const float*)d_in[19];
  const float* wih1     = (const float*)d_in[20];
  const float* whh1     = (const float*)d_in[21];
  const float* bih1     = (const float*)d_in[22];
  const float* bhh1     = (const float*)d_in[23];

  char* ws = (char*)d_ws;
  size_t off = 0;
  auto alloc = [&](size_t bytes) {
    void* p = ws + off;
    off += (bytes + 255) & ~(size_t)255;
    return p;
  };
  float* feat   = (float*)alloc((size_t)T_LEN * 192 * 4);
  float* pre    = (float*)alloc((size_t)T_LEN * 1024 * 4);
  float* hs0    = (float*)alloc((size_t)T_LEN * 256 * 4);
  float* obs_wT = (float*)alloc(1600 * 128 * 4);
  float* wih0T  = (float*)alloc(192 * 1024 * 4);
  float* wih1T  = (float*)alloc(256 * 1024 * 4);
  _Float16* wfrag = (_Float16*)alloc((size_t)2 * 262144 * 2);
  float* bias0  = (float*)alloc(1024 * 4);
  float* bias1  = (float*)alloc(1024 * 4);
  float* h0f = (float*)alloc(256 * 4);
  float* c0f = (float*)alloc(256 * 4);
  float* h1f = (float*)alloc(256 * 4);
  float* c1f = (float*)alloc(256 * 4);

  prep_kernel<<<2048, 256, 0, stream>>>(obs_w, wih0, wih1, whh0, whh1,
                                        bih0, bhh0, bih1, bhh1,
                                        obs_wT, wih0T, wih1T, wfrag, bias0, bias1);
  encoder_kernel<<<T_LEN / ETS, 256, 0, stream>>>(fov, own_pos, opponent, cost, action,
      conv1_w, conv1_b, conv2_w, conv2_b, obs_wT, obs_b, pos_w, pos_b, opp_w, opp_b,
      act_emb, feat);
  gemm_bias_kernel<<<4096, 256, 0, stream>>>(feat, wih0T, bias0, pre, T_LEN, 1024, 192);
  lstm_mfma_kernel<<<1, 512, 0, stream>>>(pre, wfrag, hs0, h0f, c0f, 1);
  gemm_bias_kernel<<<4096, 256, 0, stream>>>(hs0, wih1T, bias1, pre, T_LEN, 1024, 256);
  lstm_mfma_kernel<<<1, 512, 0, stream>>>(pre, wfrag + 262144, nullptr, h1f, c1f, 0);
  finalize_kernel<<<5, 256, 0, stream>>>(h0f, c0f, h1f, c1f, (float*)d_out);
}

// Round 3
// 54736.066 us; speedup vs baseline: 2.7794x; 2.7794x over previous
//
#include <hip/hip_runtime.h>
#include <hip/hip_bf16.h>
#include <cstdint>
#include <cstddef>

#define T_LEN 16384
#define ETS 4
#define C1T 1796

typedef _Float16 half8 __attribute__((ext_vector_type(8)));
typedef float f32x4 __attribute__((ext_vector_type(4)));

// ---------------- prep: transposes + bias sums + f16 MFMA weight fragments ----------------
// Row permutation: p = 4*u + g  ->  orig row = g*256 + u   (gates i,f,g,o contiguous per unit)
__global__ void prep_kernel(const float* __restrict__ obs_w,
                            const float* __restrict__ wih0,
                            const float* __restrict__ wih1,
                            const float* __restrict__ whh0,
                            const float* __restrict__ whh1,
                            const float* __restrict__ bih0, const float* __restrict__ bhh0,
                            const float* __restrict__ bih1, const float* __restrict__ bhh1,
                            float* __restrict__ obs_wT,    // [1600][128]
                            float* __restrict__ wih0T,     // [192][1024] permuted cols, zero-pad k>=177
                            float* __restrict__ wih1T,     // [256][1024] permuted cols
                            _Float16* __restrict__ wfrag,  // [2][64rb][8kb][64lane][8]
                            float* __restrict__ bias0, float* __restrict__ bias1) {
  int i = blockIdx.x * blockDim.x + threadIdx.x;   // 2048*256 = 524288 threads
  {
    int layer = i >> 18;
    int r = i & 262143;
    int rb = r >> 12;
    int kb = (r >> 9) & 7;
    int lane = (r >> 3) & 63;
    int j = r & 7;
    int row_p = rb * 16 + (lane & 15);
    int k = kb * 32 + (lane >> 4) * 8 + j;
    int orig = (row_p & 3) * 256 + (row_p >> 2);
    const float* src = layer ? whh1 : whh0;
    wfrag[i] = (_Float16)src[orig * 256 + k];
  }
  if (i < 1600 * 128) { int k = i >> 7, o = i & 127; obs_wT[i] = obs_w[o * 1600 + k]; }
  if (i < 192 * 1024) {
    int k = i >> 10, p = i & 1023;
    int orig = (p & 3) * 256 + (p >> 2);
    wih0T[i] = (k < 177) ? wih0[orig * 177 + k] : 0.f;
  }
  if (i < 256 * 1024) {
    int k = i >> 10, p = i & 1023;
    int orig = (p & 3) * 256 + (p >> 2);
    wih1T[i] = wih1[orig * 256 + k];
  }
  if (i < 1024) {
    int orig = (i & 3) * 256 + (i >> 2);
    bias0[i] = bih0[orig] + bhh0[orig];
    bias1[i] = bih1[orig] + bhh1[orig];
  }
}

// ---------------- encoder (unchanged, verified) ----------------
__global__ __launch_bounds__(256) void encoder_kernel(
    const float* __restrict__ fov, const float* __restrict__ own_pos,
    const float* __restrict__ opponent, const float* __restrict__ cost,
    const int* __restrict__ action,
    const float* __restrict__ w1, const float* __restrict__ b1,
    const float* __restrict__ w2, const float* __restrict__ b2,
    const float* __restrict__ obs_wT, const float* __restrict__ obs_b,
    const float* __restrict__ pos_w, const float* __restrict__ pos_b,
    const float* __restrict__ opp_w, const float* __restrict__ opp_b,
    const float* __restrict__ act_emb,
    float* __restrict__ feat) {
  __shared__ float w1s[864];
  __shared__ float b1s[32];
  __shared__ float inp[ETS * 3 * 7 * 7];
  __shared__ __align__(16) float c1[ETS * C1T];
  __shared__ __align__(16) float c2s[1600 * ETS];
  __shared__ float red[4 * 128];
  int tid = threadIdx.x;
  int t0 = blockIdx.x * ETS;

  for (int i = tid; i < 864; i += 256) w1s[i] = w1[i];
  if (tid < 32) b1s[tid] = b1[tid];
  for (int i = tid; i < ETS * 3 * 49; i += 256) inp[i] = 0.f;
  for (int i = tid; i < ETS * C1T; i += 256) c1[i] = 0.f;
  __syncthreads();
  for (int i = tid; i < ETS * 75; i += 256) {
    int t = i / 75, r = i % 75;
    int y = r / 15, x = (r / 3) % 5, ch = r % 3;
    inp[((t * 3 + ch) * 7 + (y + 1)) * 7 + (x + 1)] = fov[(size_t)(t0 + t) * 75 + r];
  }
  __syncthreads();
  for (int i = tid; i < ETS * 800; i += 256) {
    int t = i / 800, r = i % 800;
    int oc = r / 25, p = r % 25, y = p / 5, x = p % 5;
    float s = b1s[oc];
#pragma unroll
    for (int ch = 0; ch < 3; ++ch)
#pragma unroll
      for (int ky = 0; ky < 3; ++ky)
#pragma unroll
        for (int kx = 0; kx < 3; ++kx)
          s += inp[((t * 3 + ch) * 7 + y + ky) * 7 + x + kx] * w1s[oc * 27 + ch * 9 + ky * 3 + kx];
    c1[t * C1T + (oc * 7 + y + 1) * 8 + (x + 1)] = fmaxf(s, 0.f);
  }
  __syncthreads();
  {
    int oc = tid >> 2, tt = tid & 3;
    float acc[25];
    float bv = b2[oc];
#pragma unroll
    for (int p = 0; p < 25; ++p) acc[p] = bv;
    for (int ic = 0; ic < 32; ++ic) {
      float pl[56];
      const float* base = &c1[tt * C1T + ic * 56];
#pragma unroll
      for (int q = 0; q < 14; ++q) {
        float4 v = *(const float4*)(base + q * 4);
        pl[q * 4 + 0] = v.x; pl[q * 4 + 1] = v.y; pl[q * 4 + 2] = v.z; pl[q * 4 + 3] = v.w;
      }
      const float* wrow = &w2[(size_t)(oc * 32 + ic) * 9];
#pragma unroll
      for (int ky = 0; ky < 3; ++ky)
#pragma unroll
        for (int kx = 0; kx < 3; ++kx) {
          float wv = wrow[ky * 3 + kx];
#pragma unroll
          for (int p = 0; p < 25; ++p) {
            int y = p / 5, x = p % 5;
            acc[p] += pl[(y + ky) * 8 + (x + kx)] * wv;
          }
        }
    }
#pragma unroll
    for (int p = 0; p < 25; ++p)
      c2s[(oc * 25 + p) * ETS + tt] = fmaxf(acc[p], 0.f);
  }
  __syncthreads();
  {
    int o = tid & 127, kh = tid >> 7;
    float a0 = 0, a1 = 0, a2 = 0, a3 = 0;
    for (int k = kh * 800; k < kh * 800 + 800; ++k) {
      float wv = obs_wT[k * 128 + o];
      float4 cv = *(const float4*)&c2s[k * ETS];
      a0 += cv.x * wv; a1 += cv.y * wv; a2 += cv.z * wv; a3 += cv.w * wv;
    }
    if (kh == 1) { red[0 * 128 + o] = a0; red[1 * 128 + o] = a1; red[2 * 128 + o] = a2; red[3 * 128 + o] = a3; }
    __syncthreads();
    if (kh == 0) {
      float ob = obs_b[o];
      feat[(size_t)(t0 + 0) * 192 + o] = a0 + red[0 * 128 + o] + ob;
      feat[(size_t)(t0 + 1) * 192 + o] = a1 + red[1 * 128 + o] + ob;
      feat[(size_t)(t0 + 2) * 192 + o] = a2 + red[2 * 128 + o] + ob;
      feat[(size_t)(t0 + 3) * 192 + o] = a3 + red[3 * 128 + o] + ob;
    }
  }
  if (tid < 64) {
    int t = tid >> 4, f = tid & 15;
    int ti = t0 + t;
    float px = own_pos[ti * 2 + 0] / 25.f, py = own_pos[ti * 2 + 1] / 25.f;
    float pe = pos_b[f] + px * pos_w[f * 2 + 0] + py * pos_w[f * 2 + 1];
    float o0 = opponent[ti * 3 + 0] / 25.f, o1 = opponent[ti * 3 + 1] / 25.f, o2 = opponent[ti * 3 + 2] / 150.f;
    float oe = opp_b[f] + o0 * opp_w[f * 3 + 0] + o1 * opp_w[f * 3 + 1] + o2 * opp_w[f * 3 + 2];
    float ae = act_emb[action[ti] * 16 + f];
    size_t fb = (size_t)ti * 192;
    feat[fb + 128 + f] = pe;
    feat[fb + 144 + f] = oe;
    feat[fb + 160 + f] = ae;
    if (f == 0) feat[fb + 176] = cost[ti];
    if (f < 15) feat[fb + 177 + f] = 0.f;
  }
}

// ---------------- fp32 tiled GEMM (unchanged, verified) ----------------
__global__ __launch_bounds__(256) void gemm_bias_kernel(
    const float* __restrict__ A, const float* __restrict__ B,
    const float* __restrict__ bias, float* __restrict__ C,
    int M, int N, int K) {
  __shared__ __align__(16) float As[32][68];
  __shared__ __align__(16) float Bs[32][68];
  int tid = threadIdx.x;
  int mb = M >> 6;
  int bm = blockIdx.x & (mb - 1);
  int bn = blockIdx.x / mb;
  int tx = tid & 15, ty = tid >> 4;
  float acc[4][4];
#pragma unroll
  for (int i = 0; i < 4; i++)
#pragma unroll
    for (int j = 0; j < 4; j++) acc[i][j] = 0.f;
  for (int k0 = 0; k0 < K; k0 += 32) {
#pragma unroll
    for (int i = 0; i < 2; ++i) {
      int id = tid + i * 256;
      int m = id >> 3, kq = id & 7;
      float4 v = *(const float4*)&A[(size_t)(bm * 64 + m) * K + k0 + kq * 4];
      As[kq * 4 + 0][m] = v.x; As[kq * 4 + 1][m] = v.y; As[kq * 4 + 2][m] = v.z; As[kq * 4 + 3][m] = v.w;
    }
#pragma unroll
    for (int i = 0; i < 2; ++i) {
      int id = tid + i * 256;
      int k = id >> 4, nq = id & 15;
      float4 v = *(const float4*)&B[(size_t)(k0 + k) * N + bn * 64 + nq * 4];
      *(float4*)&Bs[k][nq * 4] = v;
    }
    __syncthreads();
#pragma unroll
    for (int k = 0; k < 32; ++k) {
      float4 a4 = *(const float4*)&As[k][ty * 4];
      float4 b4 = *(const float4*)&Bs[k][tx * 4];
      float am[4] = {a4.x, a4.y, a4.z, a4.w};
      float bn4[4] = {b4.x, b4.y, b4.z, b4.w};
#pragma unroll
      for (int i = 0; i < 4; i++)
#pragma unroll
        for (int j = 0; j < 4; j++) acc[i][j] += am[i] * bn4[j];
    }
    __syncthreads();
  }
#pragma unroll
  for (int i = 0; i < 4; ++i) {
    int m = bm * 64 + ty * 4 + i;
    int n0 = bn * 64 + tx * 4;
    float4 o;
    o.x = acc[i][0] + bias[n0 + 0];
    o.y = acc[i][1] + bias[n0 + 1];
    o.z = acc[i][2] + bias[n0 + 2];
    o.w = acc[i][3] + bias[n0 + 3];
    *(float4*)&C[(size_t)m * N + n0] = o;
  }
}

// ---------------- single-CU MFMA LSTM, hybrid VGPR+LDS weight residency ----------------
// 512 threads = 8 waves (2/SIMD, 256-VGPR cap). Per wave 8 row-blocks x 8 k-blocks:
// rb 0..5 fragments VGPR-resident (192 regs), rb 6..7 LDS-resident (128 KB total),
// re-read each step as conflict-free ds_read_b128. kb-outer, acc[8], one bf at a time.
__device__ __forceinline__ float sigf(float x) {
  return __builtin_amdgcn_rcpf(1.f + __expf(-x));
}

#define WLDS_HALFS 65536            // 128 KB
#define HLDS_OFF   WLDS_HALFS       // halfs
#define SMEM_BYTES (131072 + 1024 + 4096)

__global__ __launch_bounds__(512, 2) void lstm_mfma_kernel(
    const float* __restrict__ pre,        // [T][1024] permuted gate rows
    const _Float16* __restrict__ wfrag,   // [64][8][64][8]
    float* __restrict__ hs_out,
    float* __restrict__ hfin, float* __restrict__ cfin,
    int write_hs) {
  extern __shared__ __align__(16) _Float16 smem[];
  _Float16* wlds = smem;                          // [8w][2rb][8kb][64lane][8]
  _Float16* hlds = smem + HLDS_OFF;               // [2][256]
  float* zgu = (float*)(smem + HLDS_OFF + 512);   // [256][4]

  int tid = threadIdx.x;
  int wave = tid >> 6, lane = tid & 63;
  int q = lane >> 4;
  int act = ((lane & 15) == 0);

  // VGPR-resident fragments: rb 0..5
  half8 wf[6][8];
#pragma unroll
  for (int rbi = 0; rbi < 6; ++rbi)
#pragma unroll
    for (int kb = 0; kb < 8; ++kb)
      wf[rbi][kb] = *(const half8*)&wfrag[(((size_t)(wave * 8 + rbi) * 8 + kb) * 64 + lane) * 8];

  // LDS-resident fragments: rb 6..7  (per-thread copy, coalesced 16B)
#pragma unroll
  for (int p = 0; p < 2; ++p)
#pragma unroll
    for (int kb = 0; kb < 8; ++kb) {
      half8 v = *(const half8*)&wfrag[(((size_t)(wave * 8 + 6 + p) * 8 + kb) * 64 + lane) * 8];
      *(half8*)&wlds[(((wave * 2 + p) * 8 + kb) * 64 + lane) * 8] = v;
    }

  if (tid < 256) { hlds[tid] = (_Float16)0.f; hlds[256 + tid] = (_Float16)0.f; }
  __syncthreads();

  const _Float16* wbase = &wlds[(size_t)wave * 2 * 8 * 64 * 8 + lane * 8];
  float c = 0.f, hl = 0.f;

  for (int t = 0; t < T_LEN; ++t) {
    f32x4 pv;
    if (tid < 256) pv = *(const f32x4*)&pre[(size_t)t * 1024 + tid * 4];
    const _Float16* hb = &hlds[(t & 1) * 256 + q * 8];
    f32x4 acc[8];
#pragma unroll
    for (int rbi = 0; rbi < 8; ++rbi) acc[rbi] = (f32x4){0.f, 0.f, 0.f, 0.f};
#pragma unroll
    for (int kb = 0; kb < 8; ++kb) {
      half8 bf = *(const half8*)(hb + kb * 32);
      half8 f6 = *(const half8*)(wbase + (size_t)kb * 512);           // rb6 frag
      half8 f7 = *(const half8*)(wbase + (size_t)(8 + kb) * 512);     // rb7 frag
#pragma unroll
      for (int rbi = 0; rbi < 6; ++rbi)
        acc[rbi] = __builtin_amdgcn_mfma_f32_16x16x32_f16(wf[rbi][kb], bf, acc[rbi], 0, 0, 0);
      acc[6] = __builtin_amdgcn_mfma_f32_16x16x32_f16(f6, bf, acc[6], 0, 0, 0);
      acc[7] = __builtin_amdgcn_mfma_f32_16x16x32_f16(f7, bf, acc[7], 0, 0, 0);
    }
    // scatter gates, unit-major f32x4: zgu[u] = {i,f,g,o}, u = (wave*8+rbi)*4 + q
    if (act) {
#pragma unroll
      for (int rbi = 0; rbi < 8; ++rbi)
        *(f32x4*)&zgu[(size_t)(((wave * 8 + rbi) * 4 + q)) * 4] = acc[rbi];
    }
    __syncthreads();
    if (tid < 256) {
      f32x4 zv = *(const f32x4*)&zgu[(size_t)tid * 4];
      float zi = zv.x + pv.x;
      float zf = zv.y + pv.y;
      float zt = zv.z + pv.z;
      float zo = zv.w + pv.w;
      float ig = sigf(zi);
      float fg = sigf(zf);
      float gg = 2.f * sigf(2.f * zt) - 1.f;
      float og = sigf(zo);
      c = fg * c + ig * gg;
      float hn = og * (2.f * sigf(2.f * c) - 1.f);
      hl = hn;
      hlds[((t + 1) & 1) * 256 + tid] = (_Float16)hn;
      if (write_hs) hs_out[(size_t)t * 256 + tid] = hn;
    }
    __syncthreads();
  }
  if (tid < 256) { hfin[tid] = hl; cfin[tid] = c; }
}

// ---------------- gather outputs ----------------
__global__ void finalize_kernel(const float* __restrict__ h0, const float* __restrict__ c0,
                                const float* __restrict__ h1, const float* __restrict__ c1,
                                float* __restrict__ out) {
  int i = blockIdx.x * blockDim.x + threadIdx.x;
  if (i < 256) out[i] = h1[i];
  else if (i < 512) out[i] = h0[i - 256];
  else if (i < 768) out[i] = h1[i - 512];
  else if (i < 1024) out[i] = c0[i - 768];
  else if (i < 1280) out[i] = c1[i - 1024];
}

extern "C" void kernel_launch(void* const* d_in, const int* in_sizes, int n_in,
                              void* d_out, int out_size, void* d_ws, size_t ws_size,
                              hipStream_t stream) {
  const float* fov      = (const float*)d_in[0];
  const float* own_pos  = (const float*)d_in[1];
  const float* opponent = (const float*)d_in[2];
  const float* cost     = (const float*)d_in[3];
  const int*   action   = (const int*)d_in[4];
  const float* conv1_w  = (const float*)d_in[5];
  const float* conv1_b  = (const float*)d_in[6];
  const float* conv2_w  = (const float*)d_in[7];
  const float* conv2_b  = (const float*)d_in[8];
  const float* obs_w    = (const float*)d_in[9];
  const float* obs_b    = (const float*)d_in[10];
  const float* pos_w    = (const float*)d_in[11];
  const float* pos_b    = (const float*)d_in[12];
  const float* opp_w    = (const float*)d_in[13];
  const float* opp_b    = (const float*)d_in[14];
  const float* act_emb  = (const float*)d_in[15];
  const float* wih0     = (const float*)d_in[16];
  const float* whh0     = (const float*)d_in[17];
  const float* bih0     = (const float*)d_in[18];
  const float* bhh0     = (const float*)d_in[19];
  const float* wih1     = (const float*)d_in[20];
  const float* whh1     = (const float*)d_in[21];
  const float* bih1     = (const float*)d_in[22];
  const float* bhh1     = (const float*)d_in[23];

  char* ws = (char*)d_ws;
  size_t off = 0;
  auto alloc = [&](size_t bytes) {
    void* p = ws + off;
    off += (bytes + 255) & ~(size_t)255;
    return p;
  };
  float* feat   = (float*)alloc((size_t)T_LEN * 192 * 4);
  float* pre    = (float*)alloc((size_t)T_LEN * 1024 * 4);
  float* hs0    = (float*)alloc((size_t)T_LEN * 256 * 4);
  float* obs_wT = (float*)alloc(1600 * 128 * 4);
  float* wih0T  = (float*)alloc(192 * 1024 * 4);
  float* wih1T  = (float*)alloc(256 * 1024 * 4);
  _Float16* wfrag = (_Float16*)alloc((size_t)2 * 262144 * 2);
  float* bias0  = (float*)alloc(1024 * 4);
  float* bias1  = (float*)alloc(1024 * 4);
  float* h0f = (float*)alloc(256 * 4);
  float* c0f = (float*)alloc(256 * 4);
  float* h1f = (float*)alloc(256 * 4);
  float* c1f = (float*)alloc(256 * 4);

  static int lds_attr_set = 0;
  if (!lds_attr_set) {
    hipFuncSetAttribute((const void*)lstm_mfma_kernel,
                        hipFuncAttributeMaxDynamicSharedMemorySize, SMEM_BYTES);
    lds_attr_set = 1;
  }

  prep_kernel<<<2048, 256, 0, stream>>>(obs_w, wih0, wih1, whh0, whh1,
                                        bih0, bhh0, bih1, bhh1,
                                        obs_wT, wih0T, wih1T, wfrag, bias0, bias1);
  encoder_kernel<<<T_LEN / ETS, 256, 0, stream>>>(fov, own_pos, opponent, cost, action,
      conv1_w, conv1_b, conv2_w, conv2_b, obs_wT, obs_b, pos_w, pos_b, opp_w, opp_b,
      act_emb, feat);
  gemm_bias_kernel<<<4096, 256, 0, stream>>>(feat, wih0T, bias0, pre, T_LEN, 1024, 192);
  lstm_mfma_kernel<<<1, 512, SMEM_BYTES, stream>>>(pre, wfrag, hs0, h0f, c0f, 1);
  gemm_bias_kernel<<<4096, 256, 0, stream>>>(hs0, wih1T, bias1, pre, T_LEN, 1024, 256);
  lstm_mfma_kernel<<<1, 512, SMEM_BYTES, stream>>>(pre, wfrag + 262144, nullptr, h1f, c1f, 0);
  finalize_kernel<<<5, 256, 0, stream>>>(h0f, c0f, h1f, c1f, (float*)d_out);
}